// Round 8
// baseline (1014.947 us; speedup 1.0000x reference)
//
#include <hip/hip_runtime.h>
#include <hip/hip_bf16.h>
#include <hip/hip_cooperative_groups.h>

namespace cg = cooperative_groups;

#define N_NODES 50000
#define N_EDGES 800000
#define SCAN_BS 256
#define SCAN_NB ((N_NODES + SCAN_BS - 1) / SCAN_BS)   // 196

typedef __attribute__((ext_vector_type(8))) short bf16x8;
typedef __attribute__((ext_vector_type(4))) float f32x4;

__device__ __forceinline__ ushort f2bf(float f) {
    unsigned u = __float_as_uint(f);
    return (ushort)((u + 0x7fffu + ((u >> 16) & 1u)) >> 16);
}
__device__ __forceinline__ float bf2f(ushort u) {
    return __uint_as_float(((unsigned)u) << 16);
}

struct MegaParams {
    const float* x;
    const int* esrc;
    const int* edst;
    const float *Ws1, *bs1, *Ws2, *bs2, *Wm1, *bm1, *Wm21, *bm21, *Wm22, *bm22;
    const float *Watt, *batt, *Wfc, *bfc;
    float* out;
    int* hist; int* cursor; int* row_ptr; int* bsum;
    int2* edge_data; float* dinv;
    ushort *xb, *agg_x, *cat1, *bufB, *comb;
    ushort *Wcat_t, *Ws2t, *Wm22t, *Wfct;
    float* bcat;
};

// ---------------------------------------------------------------------------
// per-node gather aggregation (one wave), bf16 in/out, fp32 accumulate
// ---------------------------------------------------------------------------
template<int C>
__device__ __forceinline__ void agg_node(const ushort* __restrict__ X, int ldx,
                                         ushort* __restrict__ Y, int ldy,
                                         const int* __restrict__ row_ptr,
                                         const int2* __restrict__ edge_data,
                                         const float* __restrict__ dinv,
                                         int wid, int lane) {
    constexpr int CG = C / 8;       // lanes per row
    constexpr int SLOTS = 64 / CG;  // 2 for C=256, 4 for C=128
    const int cgi = lane & (CG - 1);
    const int slot = lane / CG;
    const float di = dinv[wid];
    float acc[8] = {0.f, 0.f, 0.f, 0.f, 0.f, 0.f, 0.f, 0.f};

    auto fma_row = [&](uint4 v, float w) {
        acc[0] = fmaf(w, __uint_as_float(v.x << 16), acc[0]);
        acc[1] = fmaf(w, __uint_as_float(v.x & 0xffff0000u), acc[1]);
        acc[2] = fmaf(w, __uint_as_float(v.y << 16), acc[2]);
        acc[3] = fmaf(w, __uint_as_float(v.y & 0xffff0000u), acc[3]);
        acc[4] = fmaf(w, __uint_as_float(v.z << 16), acc[4]);
        acc[5] = fmaf(w, __uint_as_float(v.z & 0xffff0000u), acc[5]);
        acc[6] = fmaf(w, __uint_as_float(v.w << 16), acc[6]);
        acc[7] = fmaf(w, __uint_as_float(v.w & 0xffff0000u), acc[7]);
    };

    if (slot == 0) {
        uint4 v = *(const uint4*)&X[(size_t)wid * ldx + cgi * 8];
        fma_row(v, di * di);
    }
    const int e0 = row_ptr[wid], e1 = row_ptr[wid + 1];
    int e = e0 + slot;
    for (; e + 3 * SLOTS < e1; e += 4 * SLOTS) {
        const int2 d0 = edge_data[e];
        const int2 d1 = edge_data[e + SLOTS];
        const int2 d2 = edge_data[e + 2 * SLOTS];
        const int2 d3 = edge_data[e + 3 * SLOTS];
        const uint4 v0 = *(const uint4*)&X[(size_t)d0.x * ldx + cgi * 8];
        const uint4 v1 = *(const uint4*)&X[(size_t)d1.x * ldx + cgi * 8];
        const uint4 v2 = *(const uint4*)&X[(size_t)d2.x * ldx + cgi * 8];
        const uint4 v3 = *(const uint4*)&X[(size_t)d3.x * ldx + cgi * 8];
        fma_row(v0, di * __int_as_float(d0.y));
        fma_row(v1, di * __int_as_float(d1.y));
        fma_row(v2, di * __int_as_float(d2.y));
        fma_row(v3, di * __int_as_float(d3.y));
    }
    for (; e < e1; e += SLOTS) {
        const int2 d0 = edge_data[e];
        const uint4 v0 = *(const uint4*)&X[(size_t)d0.x * ldx + cgi * 8];
        fma_row(v0, di * __int_as_float(d0.y));
    }
#pragma unroll
    for (int j = 0; j < 8; ++j) {
        if (SLOTS == 4) acc[j] += __shfl_xor(acc[j], 16);
        if (SLOTS >= 2) acc[j] += __shfl_xor(acc[j], 32);
    }
    if (slot == 0) {
        uint4 o;
        o.x = (uint)f2bf(acc[0]) | ((uint)f2bf(acc[1]) << 16);
        o.y = (uint)f2bf(acc[2]) | ((uint)f2bf(acc[3]) << 16);
        o.z = (uint)f2bf(acc[4]) | ((uint)f2bf(acc[5]) << 16);
        o.w = (uint)f2bf(acc[6]) | ((uint)f2bf(acc[7]) << 16);
        *(uint4*)&Y[(size_t)wid * ldy + cgi * 8] = o;
    }
}

// ---------------------------------------------------------------------------
// 128x128 MFMA GEMM tile, K=128. A row-major bf16 staged to LDS.
// ---------------------------------------------------------------------------
__device__ __forceinline__ void gemm128_tile(char* smem,
        const ushort* __restrict__ A, int lda,
        const ushort* __restrict__ Wt, const float* __restrict__ bias,
        ushort* __restrict__ Y, int ldy, int rb, int cb, int M, int tid) {
    const int lane = tid & 63;
    const int w = tid >> 6;
    {
        const int rowbase = tid >> 4;
        const int seg = tid & 15;
#pragma unroll
        for (int it = 0; it < 8; ++it) {
            int row = it * 16 + rowbase;
            uint4 v = make_uint4(0u, 0u, 0u, 0u);
            int r = rb + row;
            if (r < M) v = *(const uint4*)&A[(size_t)r * lda + seg * 8];
            *(uint4*)&smem[row * 272 + seg * 16] = v;
        }
    }
    __syncthreads();

    f32x4 acc[2][8];
#pragma unroll
    for (int i = 0; i < 2; ++i)
#pragma unroll
        for (int j = 0; j < 8; ++j) acc[i][j] = (f32x4){0.f, 0.f, 0.f, 0.f};

    const int arow0 = w * 32 + (lane & 15);
    const int kq = (lane >> 4) * 8;
    const int ccol = lane & 15;
#pragma unroll
    for (int ks = 0; ks < 4; ++ks) {
        const int k0 = ks * 32;
        const bf16x8 a0 = *(const bf16x8*)&smem[arow0 * 272 + (k0 + kq) * 2];
        const bf16x8 a1 = *(const bf16x8*)&smem[(arow0 + 16) * 272 + (k0 + kq) * 2];
#pragma unroll
        for (int ct = 0; ct < 8; ++ct) {
            const bf16x8 b = *(const bf16x8*)&Wt[(size_t)(cb + ct * 16 + ccol) * 128 + k0 + kq];
            acc[0][ct] = __builtin_amdgcn_mfma_f32_16x16x32_bf16(a0, b, acc[0][ct], 0, 0, 0);
            acc[1][ct] = __builtin_amdgcn_mfma_f32_16x16x32_bf16(a1, b, acc[1][ct], 0, 0, 0);
        }
    }

    const int rowq = (lane >> 4) * 4;
#pragma unroll
    for (int rt = 0; rt < 2; ++rt) {
#pragma unroll
        for (int ct = 0; ct < 8; ++ct) {
            const int col = cb + ct * 16 + ccol;
            const float bcol = bias[col];
#pragma unroll
            for (int r = 0; r < 4; ++r) {
                const int row = rb + w * 32 + rt * 16 + rowq + r;
                if (row >= M) continue;
                Y[(size_t)row * ldy + col] = f2bf(fmaxf(acc[rt][ct][r] + bcol, 0.f));
            }
        }
    }
    __syncthreads();
}

// ---------------------------------------------------------------------------
// layer-2 tile: branch 0 -> h_struct, branch 1 -> h2 + in-epilogue attention
// ---------------------------------------------------------------------------
__device__ __forceinline__ void gemm2_tile(char* smem, const MegaParams& p,
                                           int rb, int branch, int tid) {
    const int lane = tid & 63;
    const int w = tid >> 6;
    const int M = N_NODES;
    const ushort* A = p.bufB + (branch ? 128 : 0);
    const ushort* Wt = branch ? p.Wm22t : p.Ws2t;
    const float* bias = branch ? p.bm22 : p.bs2;

    {
        const int rowbase = tid >> 4;
        const int seg = tid & 15;
#pragma unroll
        for (int it = 0; it < 8; ++it) {
            int row = it * 16 + rowbase;
            uint4 v = make_uint4(0u, 0u, 0u, 0u);
            int r = rb + row;
            if (r < M) v = *(const uint4*)&A[(size_t)r * 256 + seg * 8];
            *(uint4*)&smem[row * 272 + seg * 16] = v;
        }
    }
    __syncthreads();

    f32x4 acc[2][8];
#pragma unroll
    for (int i = 0; i < 2; ++i)
#pragma unroll
        for (int j = 0; j < 8; ++j) acc[i][j] = (f32x4){0.f, 0.f, 0.f, 0.f};

    const int arow0 = w * 32 + (lane & 15);
    const int kq = (lane >> 4) * 8;
    const int ccol = lane & 15;
#pragma unroll
    for (int ks = 0; ks < 4; ++ks) {
        const int k0 = ks * 32;
        const bf16x8 a0 = *(const bf16x8*)&smem[arow0 * 272 + (k0 + kq) * 2];
        const bf16x8 a1 = *(const bf16x8*)&smem[(arow0 + 16) * 272 + (k0 + kq) * 2];
#pragma unroll
        for (int ct = 0; ct < 8; ++ct) {
            const bf16x8 b = *(const bf16x8*)&Wt[(size_t)(ct * 16 + ccol) * 128 + k0 + kq];
            acc[0][ct] = __builtin_amdgcn_mfma_f32_16x16x32_bf16(a0, b, acc[0][ct], 0, 0, 0);
            acc[1][ct] = __builtin_amdgcn_mfma_f32_16x16x32_bf16(a1, b, acc[1][ct], 0, 0, 0);
        }
    }

    const int quad = lane >> 4;
    if (branch == 0) {
#pragma unroll
        for (int rt = 0; rt < 2; ++rt) {
#pragma unroll
            for (int ct = 0; ct < 8; ++ct) {
                const int col = ct * 16 + ccol;
                const float bcol = bias[col];
#pragma unroll
                for (int r = 0; r < 4; ++r) {
                    const int row = rb + w * 32 + rt * 16 + quad * 4 + r;
                    if (row >= M) continue;
                    p.comb[(size_t)row * 256 + col] = f2bf(fmaxf(acc[rt][ct][r] + bcol, 0.f));
                }
            }
        }
    } else {
#pragma unroll
        for (int rt = 0; rt < 2; ++rt)
#pragma unroll
            for (int ct = 0; ct < 8; ++ct) {
                const float bcol = bias[ct * 16 + ccol];
#pragma unroll
                for (int r = 0; r < 4; ++r)
                    acc[rt][ct][r] = fmaxf(acc[rt][ct][r] + bcol, 0.f);
            }
        float wv[8];
#pragma unroll
        for (int ct = 0; ct < 8; ++ct) wv[ct] = p.Watt[ct * 16 + ccol];
        const float ba = p.batt[0];
#pragma unroll
        for (int rt = 0; rt < 2; ++rt) {
#pragma unroll
            for (int r = 0; r < 4; ++r) {
                const int row0 = rb + w * 32 + rt * 16 + quad * 4 + r;
                const int rowc = (row0 < M) ? row0 : (M - 1);
                const ushort* h1row = &p.cat1[(size_t)rowc * 384 + 256];
                float bp = 0.f, ap = 0.f;
#pragma unroll
                for (int ct = 0; ct < 8; ++ct) {
                    bp += acc[rt][ct][r] * wv[ct];
                    ap += bf2f(h1row[ct * 16 + ccol]) * wv[ct];
                }
#pragma unroll
                for (int off = 1; off < 16; off <<= 1) {
                    bp += __shfl_xor(bp, off);
                    ap += __shfl_xor(ap, off);
                }
                const float a = ap + ba, b = bp + ba;
                const float m = fmaxf(a, b);
                const float ea = __expf(a - m), eb = __expf(b - m);
                const float inv = 1.f / (ea + eb);
                const float wa = ea * inv, wb = eb * inv;
                if (row0 < M) {
#pragma unroll
                    for (int ct = 0; ct < 8; ++ct) {
                        const float h1 = bf2f(h1row[ct * 16 + ccol]);
                        p.comb[(size_t)row0 * 256 + 128 + ct * 16 + ccol] =
                            f2bf(fmaf(wa, h1, wb * acc[rt][ct][r]));
                    }
                }
            }
        }
    }
    __syncthreads();
}

// ---------------------------------------------------------------------------
// fc tile: BM=64, K=256, N=64, fp32 out
// ---------------------------------------------------------------------------
__device__ __forceinline__ void fc_tile(char* smem,
        const ushort* __restrict__ A, const ushort* __restrict__ Wt,
        const float* __restrict__ bias, float* __restrict__ Y,
        int rb, int M, int tid) {
    const int lane = tid & 63;
    const int w = tid >> 6;
    {
        const int rowbase = tid >> 5;
        const int seg = tid & 31;
#pragma unroll
        for (int it = 0; it < 8; ++it) {
            int row = it * 8 + rowbase;
            uint4 v = make_uint4(0u, 0u, 0u, 0u);
            int r = rb + row;
            if (r < M) v = *(const uint4*)&A[(size_t)r * 256 + seg * 8];
            *(uint4*)&smem[row * 528 + seg * 16] = v;
        }
    }
    __syncthreads();

    f32x4 acc[4];
#pragma unroll
    for (int j = 0; j < 4; ++j) acc[j] = (f32x4){0.f, 0.f, 0.f, 0.f};

    const int arow = w * 16 + (lane & 15);
    const int kq = (lane >> 4) * 8;
    const int ccol = lane & 15;
#pragma unroll
    for (int ks = 0; ks < 8; ++ks) {
        const int k0 = ks * 32;
        const bf16x8 a = *(const bf16x8*)&smem[arow * 528 + (k0 + kq) * 2];
#pragma unroll
        for (int ct = 0; ct < 4; ++ct) {
            const bf16x8 b = *(const bf16x8*)&Wt[(size_t)(ct * 16 + ccol) * 256 + k0 + kq];
            acc[ct] = __builtin_amdgcn_mfma_f32_16x16x32_bf16(a, b, acc[ct], 0, 0, 0);
        }
    }

    const int rowq = (lane >> 4) * 4;
#pragma unroll
    for (int ct = 0; ct < 4; ++ct) {
        const int col = ct * 16 + ccol;
        const float bcol = bias[col];
#pragma unroll
        for (int r = 0; r < 4; ++r) {
            const int row = rb + w * 16 + rowq + r;
            if (row < M) Y[(size_t)row * 64 + col] = acc[ct][r] + bcol;
        }
    }
    __syncthreads();
}

// ---------------------------------------------------------------------------
// THE mega-kernel: all phases, grid.sync() between dependent ones.
// __launch_bounds__(256,4): <=128 VGPR + 34.9KB LDS -> 4 blocks/CU.
// ---------------------------------------------------------------------------
__global__ __launch_bounds__(256, 4)
void mega_kernel(MegaParams p) {
    cg::grid_group grid = cg::this_grid();
    const int tid = threadIdx.x;
    const int gtid = blockIdx.x * 256 + tid;
    const int T = gridDim.x * 256;
    const int lane = tid & 63;
    const int gw = gtid >> 6;
    const int WG = T >> 6;

    __shared__ __align__(16) char smem[128 * 272];   // 34816 B, reused per phase
    __shared__ int pre_s;

    // ---- A0: zero hist | x->bf16 | weight packs (independent) ----
    for (int i = gtid; i < N_NODES; i += T) p.hist[i] = 0;
    {
        uint2* xb4 = (uint2*)p.xb;
        const int n4 = N_NODES * 128 / 4;
        for (int i = gtid; i < n4; i += T) {
            float4 v = *(const float4*)&p.x[(size_t)i * 4];
            uint2 o;
            o.x = (uint)f2bf(v.x) | ((uint)f2bf(v.y) << 16);
            o.y = (uint)f2bf(v.z) | ((uint)f2bf(v.w) << 16);
            xb4[i] = o;
        }
    }
    for (int idx = gtid; idx < 384 * 128; idx += T) {
        int c = idx >> 7, k = idx & 127;
        float v = (c < 128) ? p.Ws1[k * 128 + c]
                : (c < 256) ? p.Wm21[k * 128 + (c - 128)]
                            : p.Wm1[k * 128 + (c - 256)];
        p.Wcat_t[idx] = f2bf(v);
        if (idx < 384)
            p.bcat[idx] = (idx < 128) ? p.bs1[idx] : (idx < 256) ? p.bm21[idx - 128] : p.bm1[idx - 256];
        if (idx == 0) p.row_ptr[N_NODES] = N_EDGES;
    }
    for (int idx = gtid; idx < 128 * 128; idx += T) {
        int c = idx >> 7, k = idx & 127;
        p.Ws2t[idx]  = f2bf(p.Ws2[(size_t)k * 128 + c]);
        p.Wm22t[idx] = f2bf(p.Wm22[(size_t)k * 128 + c]);
    }
    for (int idx = gtid; idx < 64 * 256; idx += T) {
        int c = idx >> 8, k = idx & 255;
        p.Wfct[idx] = f2bf(p.Wfc[(size_t)k * 64 + c]);
    }
    grid.sync();

    // ---- A1: degree histogram ----
    for (int e = gtid; e < N_EDGES; e += T) atomicAdd(&p.hist[p.edst[e]], 1);
    grid.sync();

    // ---- B1: per-chunk sums + dinv ----
    for (int b = blockIdx.x; b < SCAN_NB; b += gridDim.x) {
        int* s = (int*)smem;
        int i = b * SCAN_BS + tid;
        int v = (i < N_NODES) ? p.hist[i] : 0;
        if (i < N_NODES) p.dinv[i] = rsqrtf((float)(v + 1));
        s[tid] = v;
        __syncthreads();
#pragma unroll
        for (int off = SCAN_BS / 2; off > 0; off >>= 1) {
            if (tid < off) s[tid] += s[tid + off];
            __syncthreads();
        }
        if (tid == 0) p.bsum[b] = s[0];
        __syncthreads();
    }
    grid.sync();

    // ---- B2: prefix of bsum + local exclusive scan -> row_ptr/cursor ----
    for (int b = blockIdx.x; b < SCAN_NB; b += gridDim.x) {
        int* s = (int*)smem;
        int pv = 0;
        for (int j = tid; j < b; j += SCAN_BS) pv += p.bsum[j];
        s[tid] = pv;
        __syncthreads();
#pragma unroll
        for (int off = SCAN_BS / 2; off > 0; off >>= 1) {
            if (tid < off) s[tid] += s[tid + off];
            __syncthreads();
        }
        if (tid == 0) pre_s = s[0];
        __syncthreads();
        const int pre = pre_s;
        __syncthreads();
        int i = b * SCAN_BS + tid;
        int v = (i < N_NODES) ? p.hist[i] : 0;
        s[tid] = v;
        __syncthreads();
#pragma unroll
        for (int off = 1; off < SCAN_BS; off <<= 1) {
            int tmp = (tid >= off) ? s[tid - off] : 0;
            __syncthreads();
            s[tid] += tmp;
            __syncthreads();
        }
        if (i < N_NODES) {
            int ex = s[tid] - v + pre;
            p.row_ptr[i] = ex;
            p.cursor[i]  = ex;
        }
        __syncthreads();
    }
    grid.sync();

    // ---- C: fill (src, dinv[src]) per CSR slot ----
    for (int e = gtid; e < N_EDGES; e += T) {
        int d = p.edst[e];
        int sI = p.esrc[e];
        int pos = atomicAdd(&p.cursor[d], 1);
        p.edge_data[pos] = make_int2(sI, __float_as_int(p.dinv[sI]));
    }
    grid.sync();

    // ---- D: layer-1 aggregation (C=128) ----
    for (int node = gw; node < N_NODES; node += WG)
        agg_node<128>(p.xb, 128, p.agg_x, 128, p.row_ptr, p.edge_data, p.dinv, node, lane);
    grid.sync();

    // ---- E: fused layer-1 GEMM (384 cols) ----
    {
        const int RT = (N_NODES + 127) / 128;    // 391
        for (int t = blockIdx.x; t < RT * 3; t += gridDim.x) {
            int rbi = t % RT, cbi = t / RT;
            gemm128_tile(smem, p.agg_x, 128, p.Wcat_t, p.bcat, p.cat1, 384,
                         rbi * 128, cbi * 128, N_NODES, tid);
        }
    }
    grid.sync();

    // ---- F: layer-2 aggregation (C=256) ----
    for (int node = gw; node < N_NODES; node += WG)
        agg_node<256>(p.cat1, 384, p.bufB, 256, p.row_ptr, p.edge_data, p.dinv, node, lane);
    grid.sync();

    // ---- G: layer-2 GEMMs + fused attention ----
    {
        const int RT = (N_NODES + 127) / 128;
        for (int t = blockIdx.x; t < RT * 2; t += gridDim.x) {
            int rbi = t % RT, branch = t / RT;
            gemm2_tile(smem, p, rbi * 128, branch, tid);
        }
    }
    grid.sync();

    // ---- H: final fc -> d_out ----
    {
        const int RT = (N_NODES + 63) / 64;
        for (int t = blockIdx.x; t < RT; t += gridDim.x)
            fc_tile(smem, p.comb, p.Wfct, p.bfc, p.out, t * 64, N_NODES, tid);
    }
}

// ---------------------------------------------------------------------------
extern "C" void kernel_launch(void* const* d_in, const int* in_sizes, int n_in,
                              void* d_out, int out_size, void* d_ws, size_t ws_size,
                              hipStream_t stream) {
    const int N = N_NODES, E = N_EDGES;

    MegaParams p;
    p.x    = (const float*)d_in[0];
    const int* ei = (const int*)d_in[1];
    p.esrc = ei;
    p.edst = ei + E;
    p.Ws1  = (const float*)d_in[2];  p.bs1  = (const float*)d_in[3];
    p.Ws2  = (const float*)d_in[4];  p.bs2  = (const float*)d_in[5];
    p.Wm1  = (const float*)d_in[6];  p.bm1  = (const float*)d_in[7];
    p.Wm21 = (const float*)d_in[8];  p.bm21 = (const float*)d_in[9];
    p.Wm22 = (const float*)d_in[10]; p.bm22 = (const float*)d_in[11];
    p.Watt = (const float*)d_in[12]; p.batt = (const float*)d_in[13];
    p.Wfc  = (const float*)d_in[14]; p.bfc  = (const float*)d_in[15];
    p.out  = (float*)d_out;

    char* base = (char*)d_ws;
    size_t off = 0;
    auto take = [&](size_t nbytes) -> void* {
        void* ptr = base + off;
        off += (nbytes + 255) & ~(size_t)255;
        return ptr;
    };
    p.hist      = (int*)take((size_t)N * 4);
    p.cursor    = (int*)take((size_t)N * 4);
    p.row_ptr   = (int*)take((size_t)(N + 1) * 4);
    p.bsum      = (int*)take((size_t)SCAN_NB * 4);
    p.edge_data = (int2*)take((size_t)E * 8);
    p.dinv      = (float*)take((size_t)N * 4);
    p.xb        = (ushort*)take((size_t)N * 128 * 2);
    p.agg_x     = (ushort*)take((size_t)N * 128 * 2);
    p.cat1      = (ushort*)take((size_t)N * 384 * 2);
    p.bufB      = (ushort*)take((size_t)N * 256 * 2);
    p.comb      = (ushort*)take((size_t)N * 256 * 2);
    p.Wcat_t    = (ushort*)take((size_t)384 * 128 * 2);
    p.Ws2t      = (ushort*)take((size_t)128 * 128 * 2);
    p.Wm22t     = (ushort*)take((size_t)128 * 128 * 2);
    p.Wfct      = (ushort*)take((size_t)64 * 256 * 2);
    p.bcat      = (float*)take((size_t)384 * 4);

    // grid = resident capacity (cooperative requirement); block-stride loops
    // make any grid size correct.
    int maxb = 0;
    hipOccupancyMaxActiveBlocksPerMultiprocessor(&maxb, mega_kernel, 256, 0);
    if (maxb < 1) maxb = 1;
    if (maxb > 8) maxb = 8;
    int grid = 256 * maxb;
    if (grid > 2048) grid = 2048;

    void* kargs[] = { (void*)&p };
    hipLaunchCooperativeKernel(mega_kernel, dim3(grid), dim3(256), kargs, 0, stream);
}

// Round 9
// 375.692 us; speedup vs baseline: 2.7015x; 2.7015x over previous
//
#include <hip/hip_runtime.h>
#include <hip/hip_bf16.h>

#define N_NODES 50000
#define N_EDGES 800000

#define SCAN_BS 256
#define SCAN_NB ((N_NODES + SCAN_BS - 1) / SCAN_BS)   // 196

// prep kernel block-range layout
#define PREP_CVT_NB   6250   // N*128/4 / 256
#define PREP_DEG_NB   3125   // E / 256
#define PREP_WCAT_NB  192    // 384*128 / 256
#define PREP_TP_NB    64     // 128*128 / 256 (and 64*256/256)
#define PREP_NB (PREP_CVT_NB + PREP_DEG_NB + PREP_WCAT_NB + 3 * PREP_TP_NB)

typedef __attribute__((ext_vector_type(8))) short bf16x8;
typedef __attribute__((ext_vector_type(4))) float f32x4;

__device__ __forceinline__ ushort f2bf(float f) {
    unsigned u = __float_as_uint(f);
    return (ushort)((u + 0x7fffu + ((u >> 16) & 1u)) >> 16);
}
__device__ __forceinline__ float bf2f(ushort u) {
    return __uint_as_float(((unsigned)u) << 16);
}

// ---------------------------------------------------------------------------
// Fused prep: x->bf16 cvt | degree histogram | weight packs | row_ptr[N]=E
// ---------------------------------------------------------------------------
__global__ __launch_bounds__(256)
void prep_kernel(const float* __restrict__ x, uint2* __restrict__ xb4,
                 const int* __restrict__ edst, int* __restrict__ hist,
                 const float* __restrict__ Ws1, const float* __restrict__ Wm21,
                 const float* __restrict__ Wm1,
                 const float* __restrict__ bs1, const float* __restrict__ bm21,
                 const float* __restrict__ bm1,
                 ushort* __restrict__ Wcat_t, float* __restrict__ bcat,
                 const float* __restrict__ Ws2, ushort* __restrict__ Ws2t,
                 const float* __restrict__ Wm22, ushort* __restrict__ Wm22t,
                 const float* __restrict__ Wfc, ushort* __restrict__ Wfct,
                 int* __restrict__ row_ptr) {
    const int bid = blockIdx.x;
    const int t = threadIdx.x;
    if (bid < PREP_CVT_NB) {
        int i = bid * 256 + t;
        float4 v = *(const float4*)&x[(size_t)i * 4];
        uint2 o;
        o.x = (uint)f2bf(v.x) | ((uint)f2bf(v.y) << 16);
        o.y = (uint)f2bf(v.z) | ((uint)f2bf(v.w) << 16);
        xb4[i] = o;
    } else if (bid < PREP_CVT_NB + PREP_DEG_NB) {
        int e = (bid - PREP_CVT_NB) * 256 + t;
        atomicAdd(&hist[edst[e]], 1);
    } else if (bid < PREP_CVT_NB + PREP_DEG_NB + PREP_WCAT_NB) {
        int idx = (bid - PREP_CVT_NB - PREP_DEG_NB) * 256 + t;
        int c = idx >> 7, k = idx & 127;
        float v = (c < 128) ? Ws1[k * 128 + c]
                : (c < 256) ? Wm21[k * 128 + (c - 128)]
                            : Wm1[k * 128 + (c - 256)];
        Wcat_t[idx] = f2bf(v);
        if (idx < 384) {
            bcat[idx] = (idx < 128) ? bs1[idx] : (idx < 256) ? bm21[idx - 128] : bm1[idx - 256];
        }
        if (idx == 0) row_ptr[N_NODES] = N_EDGES;
    } else if (bid < PREP_CVT_NB + PREP_DEG_NB + PREP_WCAT_NB + PREP_TP_NB) {
        int idx = (bid - PREP_CVT_NB - PREP_DEG_NB - PREP_WCAT_NB) * 256 + t;
        int c = idx >> 7, k = idx & 127;
        Ws2t[idx] = f2bf(Ws2[(size_t)k * 128 + c]);
    } else if (bid < PREP_CVT_NB + PREP_DEG_NB + PREP_WCAT_NB + 2 * PREP_TP_NB) {
        int idx = (bid - PREP_CVT_NB - PREP_DEG_NB - PREP_WCAT_NB - PREP_TP_NB) * 256 + t;
        int c = idx >> 7, k = idx & 127;
        Wm22t[idx] = f2bf(Wm22[(size_t)k * 128 + c]);
    } else {
        int idx = (bid - PREP_CVT_NB - PREP_DEG_NB - PREP_WCAT_NB - 2 * PREP_TP_NB) * 256 + t;
        int c = idx >> 8, k = idx & 255;
        Wfct[idx] = f2bf(Wfc[(size_t)k * 64 + c]);
    }
}

// ---------------------------------------------------------------------------
// scan phase 1: per-block sums of hist + dinv = rsqrt(deg+1)
// ---------------------------------------------------------------------------
__global__ __launch_bounds__(SCAN_BS)
void scan1_kernel(const int* __restrict__ hist, int* __restrict__ bsum,
                  float* __restrict__ dinv, int n) {
    __shared__ int s[SCAN_BS];
    int t = threadIdx.x;
    int i = blockIdx.x * SCAN_BS + t;
    int v = (i < n) ? hist[i] : 0;
    if (i < n) dinv[i] = rsqrtf((float)(v + 1));
    s[t] = v;
    __syncthreads();
#pragma unroll
    for (int off = SCAN_BS / 2; off > 0; off >>= 1) {
        if (t < off) s[t] += s[t + off];
        __syncthreads();
    }
    if (t == 0) bsum[blockIdx.x] = s[0];
}

// ---------------------------------------------------------------------------
// scan phase 2: own bsum-prefix + local exclusive scan -> row_ptr & cursor
// ---------------------------------------------------------------------------
__global__ __launch_bounds__(SCAN_BS)
void scan3_kernel(const int* __restrict__ hist, const int* __restrict__ bsum,
                  int* __restrict__ row_ptr, int* __restrict__ cursor, int n) {
    __shared__ int s[SCAN_BS];
    __shared__ int pre_s;
    int t = threadIdx.x;
    int b = blockIdx.x;
    int p = 0;
    for (int j = t; j < b; j += SCAN_BS) p += bsum[j];
    s[t] = p;
    __syncthreads();
#pragma unroll
    for (int off = SCAN_BS / 2; off > 0; off >>= 1) {
        if (t < off) s[t] += s[t + off];
        __syncthreads();
    }
    if (t == 0) pre_s = s[0];
    __syncthreads();
    const int pre = pre_s;
    __syncthreads();
    int i = b * SCAN_BS + t;
    int v = (i < n) ? hist[i] : 0;
    s[t] = v;
    __syncthreads();
#pragma unroll
    for (int off = 1; off < SCAN_BS; off <<= 1) {
        int tmp = (t >= off) ? s[t - off] : 0;
        __syncthreads();
        s[t] += tmp;
        __syncthreads();
    }
    if (i < n) {
        int ex = s[t] - v + pre;
        row_ptr[i] = ex;
        cursor[i]  = ex;
    }
}

__global__ void fill_kernel(const int* __restrict__ src, const int* __restrict__ dst, int E,
                            int* __restrict__ cursor, int2* __restrict__ edge_data,
                            const float* __restrict__ dinv) {
    int e = blockIdx.x * blockDim.x + threadIdx.x;
    if (e < E) {
        int d = dst[e];
        int s = src[e];
        int pos = atomicAdd(&cursor[d], 1);
        edge_data[pos] = make_int2(s, __float_as_int(dinv[s]));
    }
}

// ---------------------------------------------------------------------------
// bf16-gather aggregation, bf16 OUT. One wave per node, 4x unrolled edge loop.
// ---------------------------------------------------------------------------
template<int C>
__global__ __launch_bounds__(256)
void agg_bf16(const ushort* __restrict__ X, int ldx,
              ushort* __restrict__ Y, int ldy,
              const int* __restrict__ row_ptr,
              const int2* __restrict__ edge_data,
              const float* __restrict__ dinv, int n) {
    constexpr int CG = C / 8;       // lanes per row
    constexpr int SLOTS = 64 / CG;  // 2 for C=256, 4 for C=128
    const int wid = blockIdx.x * (blockDim.x >> 6) + (threadIdx.x >> 6);
    if (wid >= n) return;
    const int lane = threadIdx.x & 63;
    const int cg = lane & (CG - 1);
    const int slot = lane / CG;

    const float di = dinv[wid];
    float acc[8] = {0.f, 0.f, 0.f, 0.f, 0.f, 0.f, 0.f, 0.f};

    auto fma_row = [&](uint4 v, float w) {
        acc[0] = fmaf(w, __uint_as_float(v.x << 16), acc[0]);
        acc[1] = fmaf(w, __uint_as_float(v.x & 0xffff0000u), acc[1]);
        acc[2] = fmaf(w, __uint_as_float(v.y << 16), acc[2]);
        acc[3] = fmaf(w, __uint_as_float(v.y & 0xffff0000u), acc[3]);
        acc[4] = fmaf(w, __uint_as_float(v.z << 16), acc[4]);
        acc[5] = fmaf(w, __uint_as_float(v.z & 0xffff0000u), acc[5]);
        acc[6] = fmaf(w, __uint_as_float(v.w << 16), acc[6]);
        acc[7] = fmaf(w, __uint_as_float(v.w & 0xffff0000u), acc[7]);
    };

    if (slot == 0) {
        uint4 v = *(const uint4*)&X[(size_t)wid * ldx + cg * 8];
        fma_row(v, di * di);
    }
    const int e0 = row_ptr[wid], e1 = row_ptr[wid + 1];
    int e = e0 + slot;
    for (; e + 3 * SLOTS < e1; e += 4 * SLOTS) {
        const int2 d0 = edge_data[e];
        const int2 d1 = edge_data[e + SLOTS];
        const int2 d2 = edge_data[e + 2 * SLOTS];
        const int2 d3 = edge_data[e + 3 * SLOTS];
        const uint4 v0 = *(const uint4*)&X[(size_t)d0.x * ldx + cg * 8];
        const uint4 v1 = *(const uint4*)&X[(size_t)d1.x * ldx + cg * 8];
        const uint4 v2 = *(const uint4*)&X[(size_t)d2.x * ldx + cg * 8];
        const uint4 v3 = *(const uint4*)&X[(size_t)d3.x * ldx + cg * 8];
        fma_row(v0, di * __int_as_float(d0.y));
        fma_row(v1, di * __int_as_float(d1.y));
        fma_row(v2, di * __int_as_float(d2.y));
        fma_row(v3, di * __int_as_float(d3.y));
    }
    for (; e < e1; e += SLOTS) {
        const int2 d0 = edge_data[e];
        const uint4 v0 = *(const uint4*)&X[(size_t)d0.x * ldx + cg * 8];
        fma_row(v0, di * __int_as_float(d0.y));
    }
#pragma unroll
    for (int j = 0; j < 8; ++j) {
        if (SLOTS == 4) acc[j] += __shfl_xor(acc[j], 16);
        if (SLOTS >= 2) acc[j] += __shfl_xor(acc[j], 32);
    }
    if (slot == 0) {
        uint4 o;
        o.x = (uint)f2bf(acc[0]) | ((uint)f2bf(acc[1]) << 16);
        o.y = (uint)f2bf(acc[2]) | ((uint)f2bf(acc[3]) << 16);
        o.z = (uint)f2bf(acc[4]) | ((uint)f2bf(acc[5]) << 16);
        o.w = (uint)f2bf(acc[6]) | ((uint)f2bf(acc[7]) << 16);
        *(uint4*)&Y[(size_t)wid * ldy + cg * 8] = o;
    }
}

// ---------------------------------------------------------------------------
// bf16 MFMA GEMM, K=128. BM=128, BN=128, 256 threads. (layer-1 fused GEMM)
// ---------------------------------------------------------------------------
__global__ __launch_bounds__(256)
void mfma_gemm_kernel(const ushort* __restrict__ A, int lda,
                      const ushort* __restrict__ Wt,
                      const float* __restrict__ bias,
                      ushort* __restrict__ Y, int ldy, int M) {
    __shared__ char Asmem[128 * 272];
    const int tid = threadIdx.x;
    const int lane = tid & 63;
    const int w = tid >> 6;
    const int rb = blockIdx.x * 128;
    const int cb = blockIdx.y * 128;

    {
        const int rowbase = tid >> 4;
        const int seg = tid & 15;
#pragma unroll
        for (int it = 0; it < 8; ++it) {
            int row = it * 16 + rowbase;
            uint4 v = make_uint4(0u, 0u, 0u, 0u);
            int r = rb + row;
            if (r < M) v = *(const uint4*)&A[(size_t)r * lda + seg * 8];
            *(uint4*)&Asmem[row * 272 + seg * 16] = v;
        }
    }
    __syncthreads();

    f32x4 acc[2][8];
#pragma unroll
    for (int i = 0; i < 2; ++i)
#pragma unroll
        for (int j = 0; j < 8; ++j) acc[i][j] = (f32x4){0.f, 0.f, 0.f, 0.f};

    const int arow0 = w * 32 + (lane & 15);
    const int kq = (lane >> 4) * 8;
    const int ccol = lane & 15;
#pragma unroll
    for (int ks = 0; ks < 4; ++ks) {
        const int k0 = ks * 32;
        const bf16x8 a0 = *(const bf16x8*)&Asmem[arow0 * 272 + (k0 + kq) * 2];
        const bf16x8 a1 = *(const bf16x8*)&Asmem[(arow0 + 16) * 272 + (k0 + kq) * 2];
#pragma unroll
        for (int ct = 0; ct < 8; ++ct) {
            const bf16x8 b = *(const bf16x8*)&Wt[(size_t)(cb + ct * 16 + ccol) * 128 + k0 + kq];
            acc[0][ct] = __builtin_amdgcn_mfma_f32_16x16x32_bf16(a0, b, acc[0][ct], 0, 0, 0);
            acc[1][ct] = __builtin_amdgcn_mfma_f32_16x16x32_bf16(a1, b, acc[1][ct], 0, 0, 0);
        }
    }

    const int rowq = (lane >> 4) * 4;
#pragma unroll
    for (int rt = 0; rt < 2; ++rt) {
#pragma unroll
        for (int ct = 0; ct < 8; ++ct) {
            const int col = cb + ct * 16 + ccol;
            const float bcol = bias[col];
#pragma unroll
            for (int r = 0; r < 4; ++r) {
                const int row = rb + w * 32 + rt * 16 + rowq + r;
                if (row >= M) continue;
                Y[(size_t)row * ldy + col] = f2bf(fmaxf(acc[rt][ct][r] + bcol, 0.f));
            }
        }
    }
}

// ---------------------------------------------------------------------------
// Fused layer-2 + attention + fc. 512 threads (8 waves) per 128-row tile.
// Waves 0-3: h_struct = relu(bufB[:,0:128] @ Ws2 + b).
// Waves 4-7: h2 = relu(bufB[:,128:256] @ Wm22 + b), then in-register 2-way
//            softmax attention vs h1 (cat1[:,256:384]) -> h_meta.
// comb tile [h_struct | h_meta] round-trips through LDS (never global),
// then fc: out = comb @ Wfc + bfc (fp32, d_out).
// LDS: A1 [0,34816) + A2 [34816,69632); comb aliases [0,67584) afterwards.
// ---------------------------------------------------------------------------
__global__ __launch_bounds__(512, 4)
void gemm2fc_kernel(const ushort* __restrict__ bufB,
                    const ushort* __restrict__ Ws2t, const float* __restrict__ bs2,
                    const ushort* __restrict__ Wm22t, const float* __restrict__ bm22,
                    const ushort* __restrict__ cat1,
                    const float* __restrict__ Watt, const float* __restrict__ batt,
                    const ushort* __restrict__ Wfct, const float* __restrict__ bfc,
                    float* __restrict__ Y, int M) {
    __shared__ __align__(16) char smem[69632];
    const int tid = threadIdx.x;
    const int rb = blockIdx.x * 128;

    // stage A1 (bufB cols 0:128) and A2 (cols 128:256), 272B row stride
    {
        const int seg = tid & 15;
        const int rowbase = tid >> 4;   // 0..31
#pragma unroll
        for (int it = 0; it < 8; ++it) {
            int idx = it * 32 + rowbase;           // 0..255
            int region = idx >> 7;
            int row = idx & 127;
            int r = rb + row;
            uint4 v = make_uint4(0u, 0u, 0u, 0u);
            if (r < M) v = *(const uint4*)&bufB[(size_t)r * 256 + region * 128 + seg * 8];
            *(uint4*)&smem[region * 34816 + row * 272 + seg * 16] = v;
        }
    }
    __syncthreads();

    const int w = tid >> 6;         // 0..7
    const int lane = tid & 63;
    const int branch = w >> 2;      // 0: s2, 1: m22+attn
    const int wl = w & 3;
    const char* Areg = smem + branch * 34816;
    const ushort* Wt = branch ? Wm22t : Ws2t;
    const float* bias = branch ? bm22 : bs2;

    f32x4 acc[2][8];
#pragma unroll
    for (int i = 0; i < 2; ++i)
#pragma unroll
        for (int j = 0; j < 8; ++j) acc[i][j] = (f32x4){0.f, 0.f, 0.f, 0.f};

    const int arow0 = wl * 32 + (lane & 15);
    const int kq = (lane >> 4) * 8;
    const int ccol = lane & 15;
#pragma unroll
    for (int ks = 0; ks < 4; ++ks) {
        const int k0 = ks * 32;
        const bf16x8 a0 = *(const bf16x8*)&Areg[arow0 * 272 + (k0 + kq) * 2];
        const bf16x8 a1 = *(const bf16x8*)&Areg[(arow0 + 16) * 272 + (k0 + kq) * 2];
#pragma unroll
        for (int ct = 0; ct < 8; ++ct) {
            const bf16x8 b = *(const bf16x8*)&Wt[(size_t)(ct * 16 + ccol) * 128 + k0 + kq];
            acc[0][ct] = __builtin_amdgcn_mfma_f32_16x16x32_bf16(a0, b, acc[0][ct], 0, 0, 0);
            acc[1][ct] = __builtin_amdgcn_mfma_f32_16x16x32_bf16(a1, b, acc[1][ct], 0, 0, 0);
        }
    }

    // bias + relu in registers
#pragma unroll
    for (int rt = 0; rt < 2; ++rt)
#pragma unroll
        for (int ct = 0; ct < 8; ++ct) {
            const float bcol = bias[ct * 16 + ccol];
#pragma unroll
            for (int r = 0; r < 4; ++r)
                acc[rt][ct][r] = fmaxf(acc[rt][ct][r] + bcol, 0.f);
        }

    const int quad = lane >> 4;
    if (branch == 1) {
        // attention: transform acc (h2) into h_meta in-place
        float wv[8];
#pragma unroll
        for (int ct = 0; ct < 8; ++ct) wv[ct] = Watt[ct * 16 + ccol];
        const float ba = batt[0];
#pragma unroll
        for (int rt = 0; rt < 2; ++rt) {
#pragma unroll
            for (int r = 0; r < 4; ++r) {
                const int row0 = rb + wl * 32 + rt * 16 + quad * 4 + r;
                const int rowc = (row0 < M) ? row0 : (M - 1);
                const ushort* h1row = &cat1[(size_t)rowc * 384 + 256];
                float bp = 0.f, ap = 0.f;
#pragma unroll
                for (int ct = 0; ct < 8; ++ct) {
                    bp += acc[rt][ct][r] * wv[ct];
                    ap += bf2f(h1row[ct * 16 + ccol]) * wv[ct];
                }
#pragma unroll
                for (int off = 1; off < 16; off <<= 1) {
                    bp += __shfl_xor(bp, off);
                    ap += __shfl_xor(ap, off);
                }
                const float a = ap + ba, b = bp + ba;
                const float m = fmaxf(a, b);
                const float ea = __expf(a - m), eb = __expf(b - m);
                const float inv = 1.f / (ea + eb);
                const float wa = ea * inv, wb = eb * inv;
#pragma unroll
                for (int ct = 0; ct < 8; ++ct) {
                    const float h1 = bf2f(h1row[ct * 16 + ccol]);
                    acc[rt][ct][r] = fmaf(wa, h1, wb * acc[rt][ct][r]);
                }
            }
        }
    }
    __syncthreads();   // all A reads done; smem free for comb

    // write comb tile (bf16) to LDS: 528B row stride, col offset branch*128
#pragma unroll
    for (int rt = 0; rt < 2; ++rt) {
#pragma unroll
        for (int ct = 0; ct < 8; ++ct) {
            const int col = branch * 128 + ct * 16 + ccol;
#pragma unroll
            for (int r = 0; r < 4; ++r) {
                const int row = wl * 32 + rt * 16 + quad * 4 + r;
                *(ushort*)&smem[row * 528 + col * 2] = f2bf(acc[rt][ct][r]);
            }
        }
    }
    __syncthreads();

    // fc: wave w handles rows [w*16, w*16+16), K=256 from comb-LDS
    f32x4 fcacc[4];
#pragma unroll
    for (int j = 0; j < 4; ++j) fcacc[j] = (f32x4){0.f, 0.f, 0.f, 0.f};
    const int frow = w * 16 + (lane & 15);
#pragma unroll
    for (int ks = 0; ks < 8; ++ks) {
        const int k0 = ks * 32;
        const bf16x8 a = *(const bf16x8*)&smem[frow * 528 + (k0 + kq) * 2];
#pragma unroll
        for (int ct = 0; ct < 4; ++ct) {
            const bf16x8 b = *(const bf16x8*)&Wfct[(size_t)(ct * 16 + ccol) * 256 + k0 + kq];
            fcacc[ct] = __builtin_amdgcn_mfma_f32_16x16x32_bf16(a, b, fcacc[ct], 0, 0, 0);
        }
    }
#pragma unroll
    for (int ct = 0; ct < 4; ++ct) {
        const int col = ct * 16 + ccol;
        const float bcol = bfc[col];
#pragma unroll
        for (int r = 0; r < 4; ++r) {
            const int row = rb + w * 16 + quad * 4 + r;
            if (row < M) Y[(size_t)row * 64 + col] = fcacc[ct][r] + bcol;
        }
    }
}

// ---------------------------------------------------------------------------
extern "C" void kernel_launch(void* const* d_in, const int* in_sizes, int n_in,
                              void* d_out, int out_size, void* d_ws, size_t ws_size,
                              hipStream_t stream) {
    const int N = N_NODES, E = N_EDGES;
    const float* x     = (const float*)d_in[0];
    const int*   ei    = (const int*)d_in[1];
    const int*   esrc  = ei;
    const int*   edst  = ei + E;
    const float* W_s1  = (const float*)d_in[2];
    const float* b_s1  = (const float*)d_in[3];
    const float* W_s2  = (const float*)d_in[4];
    const float* b_s2  = (const float*)d_in[5];
    const float* W_m1  = (const float*)d_in[6];
    const float* b_m1  = (const float*)d_in[7];
    const float* W_m21 = (const float*)d_in[8];
    const float* b_m21 = (const float*)d_in[9];
    const float* W_m22 = (const float*)d_in[10];
    const float* b_m22 = (const float*)d_in[11];
    const float* W_att = (const float*)d_in[12];
    const float* b_att = (const float*)d_in[13];
    const float* W_fc  = (const float*)d_in[14];
    const float* b_fc  = (const float*)d_in[15];
    float* out = (float*)d_out;

    char* base = (char*)d_ws;
    size_t off = 0;
    auto take = [&](size_t nbytes) -> void* {
        void* p = base + off;
        off += (nbytes + 255) & ~(size_t)255;
        return p;
    };
    int*    hist      = (int*)take((size_t)N * 4);
    int*    cursor    = (int*)take((size_t)N * 4);
    int*    row_ptr   = (int*)take((size_t)(N + 1) * 4);
    int*    bsum      = (int*)take((size_t)SCAN_NB * 4);
    int2*   edge_data = (int2*)take((size_t)E * 8);
    float*  dinv      = (float*)take((size_t)N * 4);
    ushort* xb        = (ushort*)take((size_t)N * 128 * 2);
    ushort* agg_x     = (ushort*)take((size_t)N * 128 * 2);
    ushort* cat1      = (ushort*)take((size_t)N * 384 * 2);
    ushort* bufB      = (ushort*)take((size_t)N * 256 * 2);
    ushort* Wcat_t    = (ushort*)take((size_t)384 * 128 * 2);
    ushort* Ws2_t     = (ushort*)take((size_t)128 * 128 * 2);
    ushort* Wm22_t    = (ushort*)take((size_t)128 * 128 * 2);
    ushort* Wfc_t     = (ushort*)take((size_t)64 * 256 * 2);
    float*  bcat      = (float*)take((size_t)384 * 4);

    // 1. zero hist
    hipMemsetAsync(hist, 0, (size_t)N * 4, stream);
    // 2. fused prep
    prep_kernel<<<PREP_NB, 256, 0, stream>>>(x, (uint2*)xb, edst, hist,
                                             W_s1, W_m21, W_m1, b_s1, b_m21, b_m1,
                                             Wcat_t, bcat, W_s2, Ws2_t, W_m22, Wm22_t,
                                             W_fc, Wfc_t, row_ptr);
    // 3-4. scan
    scan1_kernel<<<SCAN_NB, SCAN_BS, 0, stream>>>(hist, bsum, dinv, N);
    scan3_kernel<<<SCAN_NB, SCAN_BS, 0, stream>>>(hist, bsum, row_ptr, cursor, N);
    // 5. fill CSR
    fill_kernel<<<(E + 255) / 256, 256, 0, stream>>>(esrc, edst, E, cursor, edge_data, dinv);

    // 6. layer-1 aggregation
    agg_bf16<128><<<(N + 3) / 4, 256, 0, stream>>>(xb, 128, agg_x, 128, row_ptr, edge_data, dinv, N);
    // 7. fused layer-1 GEMM
    dim3 gm384((N + 127) / 128, 3);
    mfma_gemm_kernel<<<gm384, 256, 0, stream>>>(agg_x, 128, Wcat_t, bcat, cat1, 384, N);
    // 8. layer-2 aggregation
    agg_bf16<256><<<(N + 3) / 4, 256, 0, stream>>>(cat1, 384, bufB, 256, row_ptr, edge_data, dinv, N);
    // 9. fused layer-2 GEMMs + attention + fc -> d_out
    gemm2fc_kernel<<<(N + 127) / 128, 512, 0, stream>>>(bufB, Ws2_t, b_s2, Wm22_t, b_m22,
                                                        cat1, W_att, b_att, Wfc_t, b_fc, out, N);
}